// Round 3
// baseline (130.523 us; speedup 1.0000x reference)
//
#include <hip/hip_runtime.h>
#include <hip/hip_cooperative_groups.h>

// Problem constants (from reference)
#define NT     101            // (SLEN - PTILE)/STEP + 1 = (208-8)/2+1
#define PTILES (NT * NT)      // 10201 tiles
#define BATCH  16
#define NSRC   100
#define NTILES (BATCH * PTILES)   // 163216
#define TOTF   (17 * NTILES)      // 2,774,672 floats = 11.1 MB
#define F4TOT  (TOTF / 4)         // 693,668 float4s (divides exactly)
#define NBLK   640
#define TPB    256

namespace cg = cooperative_groups;

// ONE cooperative dispatch, two phases:
//   phase 1: grid-stride float4 zero of the whole 11.1 MB output
//            (proven ~1.8us streaming pattern from R1's zero_fill)
//   grid.sync()
//   phase 2: 16 blocks (one per batch) scatter the ~95 on-sources/batch
//            (verbatim R1 sparse_fill logic, which passed verification)
// Rationale: R1 showed the two-phase decomposition is ~2.5us of kernel work
// but a second dispatch costs ~10us; cooperative launch gets the ordering
// inside a single dispatch. 640 blocks x 256 thr co-resident: 4 waves/block,
// ~3KB LDS, low VGPR -> 8 blocks/CU capacity = 2048 >> 640. OK.

__global__ __launch_bounds__(TPB)
void ImageEncoder_41944650613092_kernel(const float* __restrict__ locs,
                                        const float* __restrict__ fluxes,
                                        float* __restrict__ out)
{
    // ---------------- phase 1: streaming zero fill ----------------
    {
        float4* o4 = (float4*)out;
        const int stride = NBLK * TPB;
        for (int i = blockIdx.x * TPB + threadIdx.x; i < F4TOT; i += stride)
            o4[i] = make_float4(0.f, 0.f, 0.f, 0.f);
    }

    cg::this_grid().sync();

    // ---------------- phase 2: sparse scatter (16 blocks) ----------------
    if (blockIdx.x >= BATCH) return;

    __shared__ int   s_tc[TPB];
    __shared__ float s_y[TPB];
    __shared__ float s_x[TPB];

    const int s = threadIdx.x;
    const int b = blockIdx.x;

    int   tc = -1;
    float yp = 0.f, xp = 0.f;
    if (s < NSRC) {
        const float2 yx = ((const float2*)(locs + b * (NSRC * 2)))[s];
        yp = yx.x * 207.0f;
        xp = yx.y * 207.0f;
        int r = (int)floorf((yp - 2.5f) * 0.5f);
        int c = (int)floorf((xp - 2.5f) * 0.5f);
        bool ok = (r >= 0) & (r < NT) & (c >= 0) & (c < NT);
        if (ok) {
            // exact reference comparisons (bit-identical decision)
            const float ly = (float)(2 * r) + 2.5f;
            const float lx = (float)(2 * c) + 2.5f;
            ok = (yp > ly) & (yp < ly + 2.0f) & (xp > lx) & (xp < lx + 2.0f);
        }
        if (ok) tc = r * NT + c;
    }
    s_tc[s] = tc;
    s_y[s]  = yp;
    s_x[s]  = xp;
    __syncthreads();

    if (tc < 0) return;

    // stable rank among on-sources sharing this tile, and total count
    // (argsort(-is_on) is stable -> slot k = k-th on-source in s order)
    int rank = 0, cnt = 0;
    #pragma unroll 4
    for (int j = 0; j < NSRC; ++j) {
        const bool same = (s_tc[j] == tc);
        cnt  += same ? 1 : 0;
        rank += (same & (j < s)) ? 1 : 0;
    }

    // Output layout (flat f32, reference return order):
    //   [0,          NTILES)    n_sources
    //   [NTILES,     NTILES*5)  tile_locs   (NTILES,2,2)
    //   [NTILES*5,   NTILES*15) tile_fluxes (NTILES,2,5)
    //   [NTILES*15,  NTILES*17) tile_is_on  (NTILES,2)
    float* out_n = out;
    float* out_l = out + NTILES;
    float* out_f = out + (size_t)NTILES * 5;
    float* out_o = out + (size_t)NTILES * 15;

    const int t = b * PTILES + tc;

    if (rank == 0)
        out_n[t] = fminf((float)cnt, 2.0f);

    if (rank < 2) {
        const int   row = tc / NT;
        const int   col = tc - row * NT;
        const float ly  = (float)(2 * row) + 2.5f;
        const float lx  = (float)(2 * col) + 2.5f;

        // (yp-ly)*0.5f == (locs_pix-left)/scale, scale=2; value in (0,1) so
        // reference relu is a no-op. 8-byte aligned (t*4 + 2*rank is even).
        *(float2*)(out_l + (size_t)t * 4 + 2 * rank) =
            make_float2((yp - ly) * 0.5f, (xp - lx) * 0.5f);

        out_o[(size_t)t * 2 + rank] = 1.0f;

        const float* fb = fluxes + (size_t)(b * NSRC + s) * 5;
        float*       fo = out_f + (size_t)t * 10 + 5 * rank;
        #pragma unroll
        for (int j = 0; j < 5; ++j) fo[j] = fb[j];
    }
}

extern "C" void kernel_launch(void* const* d_in, const int* in_sizes, int n_in,
                              void* d_out, int out_size, void* d_ws, size_t ws_size,
                              hipStream_t stream) {
    const float* locs   = (const float*)d_in[0];   // (16, 100, 2) f32
    const float* fluxes = (const float*)d_in[1];   // (16, 100, 5) f32
    float* out = (float*)d_out;                    // 17 * NTILES f32

    void* args[] = { (void*)&locs, (void*)&fluxes, (void*)&out };
    hipLaunchCooperativeKernel(
        (const void*)ImageEncoder_41944650613092_kernel,
        dim3(NBLK), dim3(TPB), args, 0, stream);
}

// Round 4
// 76.338 us; speedup vs baseline: 1.7098x; 1.7098x over previous
//
#include <hip/hip_runtime.h>

// Problem constants (from reference)
#define NT     101            // (SLEN - PTILE)/STEP + 1 = (208-8)/2+1
#define PTILES (NT * NT)      // 10201 tiles
#define BATCH  16
#define NSRC   100
#define NTILES (BATCH * PTILES)   // 163216
#define PBLK   256            // tiles per block
#define NBLKX  ((PTILES + PBLK - 1) / PBLK)   // 40

// MEASUREMENT PROBE (R4): R0's exact body (best: 59.1us) looped reps=10 times
// inside the single dispatch. Stores are idempotent (pure function of inputs,
// every rep rewrites identical values); LDS reuse is barrier-separated; the
// empty asm with "memory" clobber stops the compiler sinking loop-invariant
// global stores out of the rep loop. Purpose: amplify the kernel's structural
// time ~10x so it crosses the rocprof top-5 cutoff (~40us) and we finally see
// ITS counters (VALUBusy / LDS bank conflicts / write BW) instead of only the
// harness's 268MB re-poison fill. Decision rule:
//   visible  -> structural cost ~6us/rep is real; optimize body next round
//   invisible -> body <~1us/rep; revert to R0 and declare roofline

__global__ __launch_bounds__(256)
void ImageEncoder_41944650613092_kernel(const float* __restrict__ locs,
                                        const float* __restrict__ fluxes,
                                        float* __restrict__ out,
                                        int reps)
{
    __shared__ int   s_cnt[2];
    __shared__ int   s_tc[NSRC];     // compacted candidate tile ids (s-order)
    __shared__ int   s_id[NSRC];     // compacted source indices
    __shared__ float s_y[NSRC];
    __shared__ float s_x[NSRC];
    __shared__ float s_f[PBLK * 10]; // flux output staging (10 KB)

    const int tid   = threadIdx.x;
    const int b     = blockIdx.y;
    const int pbase = blockIdx.x * PBLK;
    const int p     = pbase + tid;

    for (int rep = 0; rep < reps; ++rep) {

    // ---- stage + filter ----
    bool  m  = false;
    int   tc = -1;
    float yp = 0.f, xp = 0.f;
    if (tid < NSRC) {
        const float2 yx = ((const float2*)(locs + b * (NSRC * 2)))[tid];
        yp = yx.x * 207.0f;
        xp = yx.y * 207.0f;
        int r = (int)floorf((yp - 2.5f) * 0.5f);
        int c = (int)floorf((xp - 2.5f) * 0.5f);
        bool ok = (r >= 0) & (r < NT) & (c >= 0) & (c < NT);
        if (ok) {
            // exact reference comparisons (bit-identical decision)
            const float ly = (float)(2 * r) + 2.5f;
            const float lx = (float)(2 * c) + 2.5f;
            ok = (yp > ly) & (yp < ly + 2.0f) & (xp > lx) & (xp < lx + 2.0f);
        }
        tc = r * NT + c;
        m  = ok & (tc >= pbase) & (tc < pbase + PBLK);
    }

    // ---- order-preserving compaction (waves 0 and 1 only hold sources) ----
    int pos = 0;
    if (tid < 128) {
        const unsigned long long ball = __ballot(m);
        const int lane = tid & 63;
        const int wave = tid >> 6;
        if (lane == 0) s_cnt[wave] = __popcll(ball);
        pos = __popcll(ball & ((1ull << lane) - 1ull));
    }
    __syncthreads();
    if (m) {
        const int idx = ((tid >> 6) ? s_cnt[0] : 0) + pos;
        s_tc[idx] = tc;
        s_id[idx] = tid;
        s_y[idx]  = yp;
        s_x[idx]  = xp;
    }
    const int total = s_cnt[0] + s_cnt[1];
    __syncthreads();

    // ---- scan the few candidates; first two matches in s order ----
    int cnt = 0, i0 = -1, i1 = -1;
    for (int i = 0; i < total; ++i) {   // block-uniform bound, ~2-3 typical
        if (s_tc[i] == p) {
            if (cnt == 0)      i0 = i;
            else if (cnt == 1) i1 = i;
            ++cnt;
        }
    }

    // ---- build per-tile outputs ----
    float l4[4]   = {0.f, 0.f, 0.f, 0.f};
    float f10[10] = {0.f, 0.f, 0.f, 0.f, 0.f, 0.f, 0.f, 0.f, 0.f, 0.f};
    float o2[2]   = {0.f, 0.f};

    const int row = p / NT;
    const int col = p - row * NT;
    const float ly = (float)(2 * row) + 2.5f;
    const float lx = (float)(2 * col) + 2.5f;

    #pragma unroll
    for (int k = 0; k < 2; ++k) {
        const int i = (k == 0) ? i0 : i1;
        if (i >= 0) {
            l4[2 * k]     = (s_y[i] - ly) * 0.5f;   // /scale, scale = 2
            l4[2 * k + 1] = (s_x[i] - lx) * 0.5f;
            const float* fb = fluxes + (size_t)(b * NSRC + s_id[i]) * 5;
            #pragma unroll
            for (int j = 0; j < 5; ++j) f10[5 * k + j] = fb[j];
            o2[k] = 1.0f;
        }
    }

    // Output layout (flat f32, reference return order):
    //   [0,          NTILES)    n_sources
    //   [NTILES,     NTILES*5)  tile_locs   (NTILES,2,2)
    //   [NTILES*5,   NTILES*15) tile_fluxes (NTILES,2,5)
    //   [NTILES*15,  NTILES*17) tile_is_on  (NTILES,2)
    float* out_n = out;
    float* out_l = out + NTILES;
    float* out_f = out + (size_t)NTILES * 5;
    float* out_o = out + (size_t)NTILES * 15;

    const int t = b * PTILES + p;
    if (p < PTILES) {
        out_n[t] = fminf((float)cnt, 2.0f);
        *(float4*)(out_l + (size_t)t * 4) = make_float4(l4[0], l4[1], l4[2], l4[3]);
        *(float2*)(out_o + (size_t)t * 2) = make_float2(o2[0], o2[1]);
    }

    // ---- flux section: stage in LDS, store coalesced ----
    #pragma unroll
    for (int j = 0; j < 10; ++j) s_f[tid * 10 + j] = f10[j];
    __syncthreads();

    const int nvalid = min(PTILES - pbase, PBLK);      // 256, or 217 last strip
    const int nfl2   = nvalid * 5;                     // float2 count (nvalid*10/2)
    float2* dst = (float2*)(out_f + ((size_t)b * PTILES + pbase) * 10);
    const float2* src = (const float2*)s_f;
    for (int i = tid; i < nfl2; i += PBLK) dst[i] = src[i];

    // protect LDS reuse across reps; block store-sinking out of the loop
    __syncthreads();
    asm volatile("" ::: "memory");

    } // rep loop
}

extern "C" void kernel_launch(void* const* d_in, const int* in_sizes, int n_in,
                              void* d_out, int out_size, void* d_ws, size_t ws_size,
                              hipStream_t stream) {
    const float* locs   = (const float*)d_in[0];   // (16, 100, 2) f32
    const float* fluxes = (const float*)d_in[1];   // (16, 100, 5) f32
    float* out = (float*)d_out;                    // 17 * NTILES f32

    dim3 grid(NBLKX, BATCH);   // 40 x 16 = 640 blocks, one dispatch
    ImageEncoder_41944650613092_kernel<<<grid, 256, 0, stream>>>(locs, fluxes, out, 10);
}

// Round 5
// 58.740 us; speedup vs baseline: 2.2220x; 1.2996x over previous
//
#include <hip/hip_runtime.h>

// Problem constants (from reference)
#define NT     101            // (SLEN - PTILE)/STEP + 1 = (208-8)/2+1
#define PTILES (NT * NT)      // 10201 tiles
#define BATCH  16
#define NSRC   100
#define NTILES (BATCH * PTILES)   // 163216
#define PBLK   256            // tiles per block
#define NBLKX  ((PTILES + PBLK - 1) / PBLK)   // 40

// FINAL (R5 = R0 verbatim, probe reverted). Measured roofline decomposition
// (R0-R4 experiments):
//   - harness re-poison fill: 268MB @ 6.5TB/s = 40.7us (bench reset, fixed)
//   - graph/dispatch fixed overhead: ~16.5us (invariant across variants)
//   - this kernel: ~1.9us (R4 rep-loop probe slope), vs 1.7us write floor
//     for the 11.1MB output -> within ~10% of its memory roofline.
// Rejected by measurement: kernel split (+4us/dispatch), cooperative
// grid.sync (+70us), direct per-tile stores instead of LDS flux staging
// (+1.3us).
//
// Each source is "on" in at most one tile; argsort(-is_on) is stable -> the
// MAXDET=2 slots are the first two on-sources in s order; off slots are 0.
// Block = (batch, 256-tile strip). Stage 100 sources, pre-fold to candidate
// tile, ballot-compact (s-order preserved) the ~2.5 sources landing in this
// strip, per-tile scan those, write n/locs/is_on dense from registers and
// flux via LDS staging for fully-coalesced float2 streams.

__global__ __launch_bounds__(256)
void ImageEncoder_41944650613092_kernel(const float* __restrict__ locs,
                                        const float* __restrict__ fluxes,
                                        float* __restrict__ out)
{
    __shared__ int   s_cnt[2];
    __shared__ int   s_tc[NSRC];     // compacted candidate tile ids (s-order)
    __shared__ int   s_id[NSRC];     // compacted source indices
    __shared__ float s_y[NSRC];
    __shared__ float s_x[NSRC];
    __shared__ float s_f[PBLK * 10]; // flux output staging (10 KB)

    const int tid   = threadIdx.x;
    const int b     = blockIdx.y;
    const int pbase = blockIdx.x * PBLK;
    const int p     = pbase + tid;

    // ---- stage + filter ----
    bool  m  = false;
    int   tc = -1;
    float yp = 0.f, xp = 0.f;
    if (tid < NSRC) {
        const float2 yx = ((const float2*)(locs + b * (NSRC * 2)))[tid];
        yp = yx.x * 207.0f;
        xp = yx.y * 207.0f;
        int r = (int)floorf((yp - 2.5f) * 0.5f);
        int c = (int)floorf((xp - 2.5f) * 0.5f);
        bool ok = (r >= 0) & (r < NT) & (c >= 0) & (c < NT);
        if (ok) {
            // exact reference comparisons (bit-identical decision)
            const float ly = (float)(2 * r) + 2.5f;
            const float lx = (float)(2 * c) + 2.5f;
            ok = (yp > ly) & (yp < ly + 2.0f) & (xp > lx) & (xp < lx + 2.0f);
        }
        tc = r * NT + c;
        m  = ok & (tc >= pbase) & (tc < pbase + PBLK);
    }

    // ---- order-preserving compaction (waves 0 and 1 only hold sources) ----
    int pos = 0;
    if (tid < 128) {
        const unsigned long long ball = __ballot(m);
        const int lane = tid & 63;
        const int wave = tid >> 6;
        if (lane == 0) s_cnt[wave] = __popcll(ball);
        pos = __popcll(ball & ((1ull << lane) - 1ull));
    }
    __syncthreads();
    if (m) {
        const int idx = ((tid >> 6) ? s_cnt[0] : 0) + pos;
        s_tc[idx] = tc;
        s_id[idx] = tid;
        s_y[idx]  = yp;
        s_x[idx]  = xp;
    }
    const int total = s_cnt[0] + s_cnt[1];
    __syncthreads();

    // ---- scan the few candidates; first two matches in s order ----
    int cnt = 0, i0 = -1, i1 = -1;
    for (int i = 0; i < total; ++i) {   // block-uniform bound, ~2-3 typical
        if (s_tc[i] == p) {
            if (cnt == 0)      i0 = i;
            else if (cnt == 1) i1 = i;
            ++cnt;
        }
    }

    // ---- build per-tile outputs ----
    float l4[4]   = {0.f, 0.f, 0.f, 0.f};
    float f10[10] = {0.f, 0.f, 0.f, 0.f, 0.f, 0.f, 0.f, 0.f, 0.f, 0.f};
    float o2[2]   = {0.f, 0.f};

    const int row = p / NT;
    const int col = p - row * NT;
    const float ly = (float)(2 * row) + 2.5f;
    const float lx = (float)(2 * col) + 2.5f;

    #pragma unroll
    for (int k = 0; k < 2; ++k) {
        const int i = (k == 0) ? i0 : i1;
        if (i >= 0) {
            l4[2 * k]     = (s_y[i] - ly) * 0.5f;   // /scale, scale = 2
            l4[2 * k + 1] = (s_x[i] - lx) * 0.5f;
            const float* fb = fluxes + (size_t)(b * NSRC + s_id[i]) * 5;
            #pragma unroll
            for (int j = 0; j < 5; ++j) f10[5 * k + j] = fb[j];
            o2[k] = 1.0f;
        }
    }

    // Output layout (flat f32, reference return order):
    //   [0,          NTILES)    n_sources
    //   [NTILES,     NTILES*5)  tile_locs   (NTILES,2,2)
    //   [NTILES*5,   NTILES*15) tile_fluxes (NTILES,2,5)
    //   [NTILES*15,  NTILES*17) tile_is_on  (NTILES,2)
    float* out_n = out;
    float* out_l = out + NTILES;
    float* out_f = out + (size_t)NTILES * 5;
    float* out_o = out + (size_t)NTILES * 15;

    const int t = b * PTILES + p;
    if (p < PTILES) {
        out_n[t] = fminf((float)cnt, 2.0f);
        *(float4*)(out_l + (size_t)t * 4) = make_float4(l4[0], l4[1], l4[2], l4[3]);
        *(float2*)(out_o + (size_t)t * 2) = make_float2(o2[0], o2[1]);
    }

    // ---- flux section: stage in LDS, store coalesced ----
    #pragma unroll
    for (int j = 0; j < 10; ++j) s_f[tid * 10 + j] = f10[j];
    __syncthreads();

    const int nvalid = min(PTILES - pbase, PBLK);      // 256, or 217 last strip
    const int nfl2   = nvalid * 5;                     // float2 count (nvalid*10/2)
    float2* dst = (float2*)(out_f + ((size_t)b * PTILES + pbase) * 10);
    const float2* src = (const float2*)s_f;
    for (int i = tid; i < nfl2; i += PBLK) dst[i] = src[i];
}

extern "C" void kernel_launch(void* const* d_in, const int* in_sizes, int n_in,
                              void* d_out, int out_size, void* d_ws, size_t ws_size,
                              hipStream_t stream) {
    const float* locs   = (const float*)d_in[0];   // (16, 100, 2) f32
    const float* fluxes = (const float*)d_in[1];   // (16, 100, 5) f32
    float* out = (float*)d_out;                    // 17 * NTILES f32

    dim3 grid(NBLKX, BATCH);   // 40 x 16 = 640 blocks, one dispatch
    ImageEncoder_41944650613092_kernel<<<grid, 256, 0, stream>>>(locs, fluxes, out);
}